// Round 2
// baseline (507.592 us; speedup 1.0000x reference)
//
#include <hip/hip_runtime.h>

// Inputs are FLOAT32 per the reference; output FLOAT32. bf16 used internally
// for MFMA, handled as raw u16 with manual RNE converters.
typedef unsigned short u16;
typedef __attribute__((ext_vector_type(8))) short short8;   // MFMA A/B frag (8 bf16)
typedef __attribute__((ext_vector_type(4))) float f32x4;    // MFMA C/D frag

__device__ inline u16 f32_to_bf16(float f) {
  unsigned int u = __float_as_uint(f);
  u += 0x7fffu + ((u >> 16) & 1u);      // round-to-nearest-even
  return (u16)(u >> 16);
}
__device__ inline float bf16_to_f32(u16 s) {
  return __uint_as_float(((unsigned int)s) << 16);
}

// ---------------------------------------------------------------------------
// Weight repack + f32 -> bf16 hi/lo planes.
// Reference packs qkv dim j = d*48 + k*16 + h (d-major). Plane rows n = h*64+d.
//   part 0: tq rows from Wtqkv (k=0)  -> Wtq_hi/Wtq_lo
//   part 1: k  rows from Wqkv  (k=1)  -> Wk_hi/Wk_lo
//   part 2: v  rows from Wqkv  (k=2)  -> Wv_hi
//   part 3: Wout rows (no permute)    -> Woutb
__global__ void repack_w(const float* __restrict__ Wqkv, const float* __restrict__ Wtqkv,
                         const float* __restrict__ Wout,
                         u16* __restrict__ Wtq_hi, u16* __restrict__ Wtq_lo,
                         u16* __restrict__ Wk_hi,  u16* __restrict__ Wk_lo,
                         u16* __restrict__ Wv_hi,  u16* __restrict__ Woutb) {
  int r = blockIdx.x;              // 0..4095
  int part = r >> 10;
  int rr = r & 1023;
  int h = rr >> 6, d = rr & 63;
  const float* src;
  u16 *dh, *dl = nullptr;
  if (part == 0)      { src = Wtqkv + (size_t)(d * 48 + h) * 1024;      dh = Wtq_hi + (size_t)rr * 1024; dl = Wtq_lo + (size_t)rr * 1024; }
  else if (part == 1) { src = Wqkv  + (size_t)(d * 48 + 16 + h) * 1024; dh = Wk_hi  + (size_t)rr * 1024; dl = Wk_lo  + (size_t)rr * 1024; }
  else if (part == 2) { src = Wqkv  + (size_t)(d * 48 + 32 + h) * 1024; dh = Wv_hi  + (size_t)rr * 1024; }
  else                { src = Wout  + (size_t)rr * 1024;                dh = Woutb  + (size_t)rr * 1024; }
  int c = threadIdx.x * 4;
  f32x4 v = *(const f32x4*)&src[c];
  unsigned int hv[4], lv[4];
#pragma unroll
  for (int j = 0; j < 4; ++j) {
    u16 hb = f32_to_bf16(v[j]);
    hv[j] = hb;
    lv[j] = f32_to_bf16(v[j] - bf16_to_f32(hb));
  }
  uint2 ho; ho.x = hv[0] | (hv[1] << 16); ho.y = hv[2] | (hv[3] << 16);
  *(uint2*)&dh[c] = ho;
  if (dl) {
    uint2 lo; lo.x = lv[0] | (lv[1] << 16); lo.y = lv[2] | (lv[3] << 16);
    *(uint2*)&dl[c] = lo;
  }
}

// ---------------------------------------------------------------------------
__device__ inline void store_c(float* p, float v) { *p = v; }
__device__ inline void store_c(u16* p, float v) { *p = f32_to_bf16(v); }

// C = A(M,K) * B(N,K)^T. A f32 (hi/lo-split at staging), B given as bf16
// hi(/lo) planes. HILO: 3-MFMA high-precision product (err ~2^-18 rel).
// 128x128 tile, BK=32, 4 waves 2x2, wave does 4x4 16x16x32 MFMA tiles.
template <typename CT, bool HILO>
__global__ __launch_bounds__(256)
void gemm_ahl(const float* __restrict__ A, const u16* __restrict__ Bh,
              const u16* __restrict__ Bl, CT* __restrict__ C,
              int M, int N, int K) {
  __shared__ __align__(16) u16 Ahs[128][40];   // +8 pad
  __shared__ __align__(16) u16 Als[128][40];
  __shared__ __align__(16) u16 Bhs[128][40];
  __shared__ __align__(16) u16 Bls[128][40];
  const int tid = threadIdx.x;
  const int wid = tid >> 6, lane = tid & 63;
  const int g = lane >> 4, l16 = lane & 15;
  const int m0 = blockIdx.y * 128, n0 = blockIdx.x * 128;
  const int wm = (wid & 1) * 64, wn = (wid >> 1) * 64;

  f32x4 acc[4][4];
  const f32x4 zero4 = {0.f, 0.f, 0.f, 0.f};
#pragma unroll
  for (int i = 0; i < 4; ++i)
#pragma unroll
    for (int j = 0; j < 4; ++j) acc[i][j] = zero4;

  for (int k0 = 0; k0 < K; k0 += 32) {
    __syncthreads();
#pragma unroll
    for (int r = 0; r < 2; ++r) {
      int idx = tid + r * 256;        // 0..511
      int row = idx >> 2;             // 0..127
      int col = (idx & 3) * 8;        // 0,8,16,24
      const float* ap = &A[(size_t)(m0 + row) * K + k0 + col];
      f32x4 a0 = *(const f32x4*)ap;
      f32x4 a1 = *(const f32x4*)(ap + 4);
      short8 hfr, lfr;
#pragma unroll
      for (int j = 0; j < 8; ++j) {
        float v = (j < 4) ? a0[j] : a1[j - 4];
        u16 hb = f32_to_bf16(v);
        hfr[j] = (short)hb;
        if (HILO) lfr[j] = (short)f32_to_bf16(v - bf16_to_f32(hb));
      }
      *(short8*)&Ahs[row][col] = hfr;
      if (HILO) *(short8*)&Als[row][col] = lfr;
      *(uint4*)&Bhs[row][col] = *(const uint4*)&Bh[(size_t)(n0 + row) * K + k0 + col];
      if (HILO) *(uint4*)&Bls[row][col] = *(const uint4*)&Bl[(size_t)(n0 + row) * K + k0 + col];
    }
    __syncthreads();
    short8 ah[4], al[4], bh4[4], bl4[4];
#pragma unroll
    for (int mi = 0; mi < 4; ++mi) {
      ah[mi] = *(const short8*)&Ahs[wm + mi * 16 + l16][g * 8];
      if (HILO) al[mi] = *(const short8*)&Als[wm + mi * 16 + l16][g * 8];
    }
#pragma unroll
    for (int ni = 0; ni < 4; ++ni) {
      bh4[ni] = *(const short8*)&Bhs[wn + ni * 16 + l16][g * 8];
      if (HILO) bl4[ni] = *(const short8*)&Bls[wn + ni * 16 + l16][g * 8];
    }
#pragma unroll
    for (int mi = 0; mi < 4; ++mi)
#pragma unroll
      for (int ni = 0; ni < 4; ++ni) {
        acc[mi][ni] = __builtin_amdgcn_mfma_f32_16x16x32_bf16(ah[mi], bh4[ni], acc[mi][ni], 0, 0, 0);
        if (HILO) {
          acc[mi][ni] = __builtin_amdgcn_mfma_f32_16x16x32_bf16(ah[mi], bl4[ni], acc[mi][ni], 0, 0, 0);
          acc[mi][ni] = __builtin_amdgcn_mfma_f32_16x16x32_bf16(al[mi], bh4[ni], acc[mi][ni], 0, 0, 0);
        }
      }
  }
  // C/D layout: col=lane&15 (n), row=(lane>>4)*4+reg (m)
#pragma unroll
  for (int mi = 0; mi < 4; ++mi)
#pragma unroll
    for (int ni = 0; ni < 4; ++ni) {
      int row = m0 + wm + mi * 16 + g * 4;
      int col = n0 + wn + ni * 16 + l16;
#pragma unroll
      for (int r = 0; r < 4; ++r)
        store_c(&C[(size_t)(row + r) * N + col], acc[mi][ni][r]);
    }
}

// ---------------------------------------------------------------------------
// Plain bf16 GEMM: C = A(M,K) * B(N,K)^T, A/B bf16, C float (final proj).
__global__ __launch_bounds__(256)
void gemm_bt(const u16* __restrict__ A, const u16* __restrict__ B,
             float* __restrict__ C, int M, int N, int K) {
  __shared__ __align__(16) u16 As[128][40];
  __shared__ __align__(16) u16 Bs[128][40];
  const int tid = threadIdx.x;
  const int wid = tid >> 6, lane = tid & 63;
  const int g = lane >> 4, l16 = lane & 15;
  const int m0 = blockIdx.y * 128, n0 = blockIdx.x * 128;
  const int wm = (wid & 1) * 64, wn = (wid >> 1) * 64;

  f32x4 acc[4][4];
  const f32x4 zero4 = {0.f, 0.f, 0.f, 0.f};
#pragma unroll
  for (int i = 0; i < 4; ++i)
#pragma unroll
    for (int j = 0; j < 4; ++j) acc[i][j] = zero4;

  for (int k0 = 0; k0 < K; k0 += 32) {
    __syncthreads();
#pragma unroll
    for (int r = 0; r < 2; ++r) {
      int idx = tid + r * 256;
      int row = idx >> 2;
      int col = (idx & 3) * 8;
      *(uint4*)&As[row][col] = *(const uint4*)&A[(size_t)(m0 + row) * K + k0 + col];
      *(uint4*)&Bs[row][col] = *(const uint4*)&B[(size_t)(n0 + row) * K + k0 + col];
    }
    __syncthreads();
    short8 af[4], bfr[4];
#pragma unroll
    for (int mi = 0; mi < 4; ++mi)
      af[mi] = *(const short8*)&As[wm + mi * 16 + l16][g * 8];
#pragma unroll
    for (int ni = 0; ni < 4; ++ni)
      bfr[ni] = *(const short8*)&Bs[wn + ni * 16 + l16][g * 8];
#pragma unroll
    for (int mi = 0; mi < 4; ++mi)
#pragma unroll
      for (int ni = 0; ni < 4; ++ni)
        acc[mi][ni] = __builtin_amdgcn_mfma_f32_16x16x32_bf16(af[mi], bfr[ni], acc[mi][ni], 0, 0, 0);
  }
#pragma unroll
  for (int mi = 0; mi < 4; ++mi)
#pragma unroll
    for (int ni = 0; ni < 4; ++ni) {
      int row = m0 + wm + mi * 16 + g * 4;
      int col = n0 + wn + ni * 16 + l16;
#pragma unroll
      for (int r = 0; r < 4; ++r)
        C[(size_t)(row + r) * N + col] = acc[mi][ni][r];
    }
}

// ---------------------------------------------------------------------------
// Flash attention. TQ,K in f32 (energy std ~64 -> near-argmax softmax; plain
// bf16 q/k would flip weights). QK^T via bf16 hi/lo split (3 MFMAs per pair):
// err ~2^-16 rel -> energy err ~1e-3. Block = 64 q rows (4 waves x 16 rows).
__global__ __launch_bounds__(256)
void attn_fwd(const float* __restrict__ TQ, const float* __restrict__ Kf,
              const u16* __restrict__ Vb, u16* __restrict__ O) {
  const int blk = blockIdx.x;
  const int qt = blk & 31, bh = blk >> 5;
  const int h = bh & 15, b = bh >> 4;
  const int t0 = qt * 64;
  const int tid = threadIdx.x, wid = tid >> 6, lane = tid & 63;
  const int g = lane >> 4, l16 = lane & 15;

  __shared__ __align__(16) u16 Khi[32][72];   // keys x d, +8 pad
  __shared__ __align__(16) u16 Klo[32][72];
  __shared__ __align__(16) u16 Vt[64][40];    // d x keys (transposed), +8 pad
  __shared__ __align__(16) u16 Pl[4][16][40]; // per-wave P round-trip

  // Q fragments (hi/lo), rows t0 + wid*16 + l16; A-frag: [m=l16][k=g*8+j]
  short8 qhi[2], qlo[2];
  {
    const float* qb = TQ + (size_t)(b * 2048 + t0 + wid * 16 + l16) * 1024 + h * 64;
#pragma unroll
    for (int f = 0; f < 2; ++f) {
      const float* p = qb + f * 32 + g * 8;
      f32x4 v0 = *(const f32x4*)p;
      f32x4 v1 = *(const f32x4*)(p + 4);
#pragma unroll
      for (int j = 0; j < 8; ++j) {
        float q = (j < 4) ? v0[j] : v1[j - 4];
        u16 hb = f32_to_bf16(q);
        qhi[f][j] = (short)hb;
        qlo[f][j] = (short)f32_to_bf16(q - bf16_to_f32(hb));
      }
    }
  }

  float mrow[4], lrow[4];
#pragma unroll
  for (int r = 0; r < 4; ++r) { mrow[r] = -3.0e38f; lrow[r] = 0.f; }
  const f32x4 zero4 = {0.f, 0.f, 0.f, 0.f};
  f32x4 acc[4];
#pragma unroll
  for (int dt = 0; dt < 4; ++dt) acc[dt] = zero4;

  const float* Kb = Kf + (size_t)(b * 2048) * 1024 + h * 64;
  const u16* Vbp = Vb + (size_t)(b * 2048) * 1024 + h * 64;

  for (int j0 = 0; j0 < 2048; j0 += 32) {
    __syncthreads();
    {  // stage K (hi/lo) and V^T: thread -> key=tid>>3, dp=(tid&7)*8
      int key = tid >> 3, dp = (tid & 7) * 8;
      const float* ks = Kb + (size_t)(j0 + key) * 1024 + dp;
      f32x4 a = *(const f32x4*)ks;
      f32x4 c = *(const f32x4*)(ks + 4);
      short8 hv, lv;
#pragma unroll
      for (int j = 0; j < 8; ++j) {
        float kvv = (j < 4) ? a[j] : c[j - 4];
        u16 hb = f32_to_bf16(kvv);
        hv[j] = (short)hb;
        lv[j] = (short)f32_to_bf16(kvv - bf16_to_f32(hb));
      }
      *(short8*)&Khi[key][dp] = hv;
      *(short8*)&Klo[key][dp] = lv;
      short8 vv = *(const short8*)(Vbp + (size_t)(j0 + key) * 1024 + dp);
#pragma unroll
      for (int j = 0; j < 8; ++j) Vt[dp + j][key] = (u16)vv[j];
    }
    __syncthreads();

    // scores: s0 = keys j0..j0+15, s1 = keys j0+16..j0+31
    f32x4 s0 = zero4, s1 = zero4;
    {
      short8 kh0 = *(const short8*)&Khi[l16][g * 8];
      short8 kh1 = *(const short8*)&Khi[l16][32 + g * 8];
      short8 kl0 = *(const short8*)&Klo[l16][g * 8];
      short8 kl1 = *(const short8*)&Klo[l16][32 + g * 8];
      s0 = __builtin_amdgcn_mfma_f32_16x16x32_bf16(qhi[0], kh0, s0, 0, 0, 0);
      s0 = __builtin_amdgcn_mfma_f32_16x16x32_bf16(qhi[1], kh1, s0, 0, 0, 0);
      s0 = __builtin_amdgcn_mfma_f32_16x16x32_bf16(qlo[0], kh0, s0, 0, 0, 0);
      s0 = __builtin_amdgcn_mfma_f32_16x16x32_bf16(qlo[1], kh1, s0, 0, 0, 0);
      s0 = __builtin_amdgcn_mfma_f32_16x16x32_bf16(qhi[0], kl0, s0, 0, 0, 0);
      s0 = __builtin_amdgcn_mfma_f32_16x16x32_bf16(qhi[1], kl1, s0, 0, 0, 0);
      short8 kh2 = *(const short8*)&Khi[16 + l16][g * 8];
      short8 kh3 = *(const short8*)&Khi[16 + l16][32 + g * 8];
      short8 kl2 = *(const short8*)&Klo[16 + l16][g * 8];
      short8 kl3 = *(const short8*)&Klo[16 + l16][32 + g * 8];
      s1 = __builtin_amdgcn_mfma_f32_16x16x32_bf16(qhi[0], kh2, s1, 0, 0, 0);
      s1 = __builtin_amdgcn_mfma_f32_16x16x32_bf16(qhi[1], kh3, s1, 0, 0, 0);
      s1 = __builtin_amdgcn_mfma_f32_16x16x32_bf16(qlo[0], kh2, s1, 0, 0, 0);
      s1 = __builtin_amdgcn_mfma_f32_16x16x32_bf16(qlo[1], kh3, s1, 0, 0, 0);
      s1 = __builtin_amdgcn_mfma_f32_16x16x32_bf16(qhi[0], kl2, s1, 0, 0, 0);
      s1 = __builtin_amdgcn_mfma_f32_16x16x32_bf16(qhi[1], kl3, s1, 0, 0, 0);
    }
    s0 = s0 * 8.f;   // reference MULTIPLIES by sqrt(d_head)=8
    s1 = s1 * 8.f;

    // online softmax: register r = query row g*4+r; reduce over l16 (16 lanes)
#pragma unroll
    for (int r = 0; r < 4; ++r) {
      float cm = fmaxf(s0[r], s1[r]);
      cm = fmaxf(cm, __shfl_xor(cm, 1));
      cm = fmaxf(cm, __shfl_xor(cm, 2));
      cm = fmaxf(cm, __shfl_xor(cm, 4));
      cm = fmaxf(cm, __shfl_xor(cm, 8));
      float mnew = fmaxf(mrow[r], cm);
      float alpha = __expf(mrow[r] - mnew);
      float p0 = __expf(s0[r] - mnew);
      float p1 = __expf(s1[r] - mnew);
      float t = p0 + p1;
      t += __shfl_xor(t, 1); t += __shfl_xor(t, 2);
      t += __shfl_xor(t, 4); t += __shfl_xor(t, 8);
      lrow[r] = lrow[r] * alpha + t;
      mrow[r] = mnew;
#pragma unroll
      for (int dt = 0; dt < 4; ++dt) acc[dt][r] *= alpha;
      Pl[wid][g * 4 + r][l16] = f32_to_bf16(p0);
      Pl[wid][g * 4 + r][16 + l16] = f32_to_bf16(p1);
    }
    __syncthreads();
    // P as A-operand [m=l16][k=g*8+j]; V^T as B-operand [n=d][k=key]
    short8 ap = *(const short8*)&Pl[wid][l16][g * 8];
#pragma unroll
    for (int dt = 0; dt < 4; ++dt) {
      short8 bv = *(const short8*)&Vt[dt * 16 + l16][g * 8];
      acc[dt] = __builtin_amdgcn_mfma_f32_16x16x32_bf16(ap, bv, acc[dt], 0, 0, 0);
    }
  }

  // epilogue: O[b, t, h*64+d] bf16
#pragma unroll
  for (int r = 0; r < 4; ++r) {
    float inv = 1.f / lrow[r];
    int t = t0 + wid * 16 + g * 4 + r;
    size_t base = (size_t)(b * 2048 + t) * 1024 + h * 64;
#pragma unroll
    for (int dt = 0; dt < 4; ++dt)
      O[base + dt * 16 + l16] = f32_to_bf16(acc[dt][r] * inv);
  }
}

// ---------------------------------------------------------------------------
extern "C" void kernel_launch(void* const* d_in, const int* in_sizes, int n_in,
                              void* d_out, int out_size, void* d_ws, size_t ws_size,
                              hipStream_t stream) {
  const float* x     = (const float*)d_in[0];   // (2,2048,1024) f32
  const float* tx    = (const float*)d_in[1];
  const float* Wqkv  = (const float*)d_in[2];   // (3072,1024) f32
  const float* Wtqkv = (const float*)d_in[3];
  const float* Wout  = (const float*)d_in[4];   // (1024,1024) f32
  float* out = (float*)d_out;                   // (2,2048,1024) f32

  // workspace layout (bytes), total 54,525,952:
  //   0        Wtq_hi 2MB | 2M Wtq_lo | 4M Wk_hi | 6M Wk_lo | 8M Wv_hi
  //   10M      Woutb 2MB
  //   12M      TQf 16MB (f32) | 28M Kfp 16MB (f32) | 44M Vb 8MB (bf16)
  //   Ob (8MB bf16) aliases offset 0 (weight planes dead after projections)
  char* ws = (char*)d_ws;
  const size_t MB = 1048576;
  u16*   Wtq_hi = (u16*)(ws + 0 * MB);
  u16*   Wtq_lo = (u16*)(ws + 2 * MB);
  u16*   Wk_hi  = (u16*)(ws + 4 * MB);
  u16*   Wk_lo  = (u16*)(ws + 6 * MB);
  u16*   Wv_hi  = (u16*)(ws + 8 * MB);
  u16*   Woutb  = (u16*)(ws + 10 * MB);
  float* TQf    = (float*)(ws + 12 * MB);
  float* Kfp    = (float*)(ws + 28 * MB);
  u16*   Vb     = (u16*)(ws + 44 * MB);
  u16*   Ob     = (u16*)(ws + 0 * MB);   // alias over weight planes
  if (ws_size < 52 * MB) return;  // insufficient scratch -> zeros out (visible)

  repack_w<<<4096, 256, 0, stream>>>(Wqkv, Wtqkv, Wout,
                                     Wtq_hi, Wtq_lo, Wk_hi, Wk_lo, Wv_hi, Woutb);
  dim3 blk(256);
  dim3 g1(1024 / 128, 4096 / 128);  // (N/128, M/128)
  // TQ = tx @ Wtq^T (f32 out, hi/lo precision)
  gemm_ahl<float, true><<<g1, blk, 0, stream>>>(tx, Wtq_hi, Wtq_lo, TQf, 4096, 1024, 1024);
  // K = x @ Wk^T (f32 out, hi/lo precision)
  gemm_ahl<float, true><<<g1, blk, 0, stream>>>(x, Wk_hi, Wk_lo, Kfp, 4096, 1024, 1024);
  // V = x @ Wv^T (bf16 out, hi-only)
  gemm_ahl<u16, false><<<g1, blk, 0, stream>>>(x, Wv_hi, Wv_hi, Vb, 4096, 1024, 1024);
  // attention (writes Ob, which overlays the now-dead weight planes)
  attn_fwd<<<1024, blk, 0, stream>>>(TQf, Kfp, Vb, Ob);
  // out = O @ Wout^T (f32 out)
  gemm_bt<<<g1, blk, 0, stream>>>(Ob, Woutb, out, 4096, 1024, 1024);
}

// Round 3
// 441.328 us; speedup vs baseline: 1.1501x; 1.1501x over previous
//
#include <hip/hip_runtime.h>

// Inputs/outputs are FLOAT32 per the reference. bf16 used internally for MFMA,
// handled as raw u16 with manual RNE converters.
typedef unsigned short u16;
typedef __attribute__((ext_vector_type(8))) short short8;   // MFMA A/B frag (8 bf16)
typedef __attribute__((ext_vector_type(4))) float f32x4;    // MFMA C/D frag

__device__ inline u16 f32_to_bf16(float f) {
  unsigned int u = __float_as_uint(f);
  u += 0x7fffu + ((u >> 16) & 1u);      // round-to-nearest-even
  return (u16)(u >> 16);
}
__device__ inline float bf16_to_f32(u16 s) {
  return __uint_as_float(((unsigned int)s) << 16);
}

#if __has_builtin(__builtin_amdgcn_exp2f)
#define EXP2F(x) __builtin_amdgcn_exp2f(x)
#else
#define EXP2F(x) exp2f(x)
#endif

// ---------------------------------------------------------------------------
// Weight repack + f32 -> bf16 hi/lo planes. Reference packs qkv dim
// j = d*48 + k*16 + h (d-major). Plane rows n = h*64+d.
__global__ void repack_w(const float* __restrict__ Wqkv, const float* __restrict__ Wtqkv,
                         const float* __restrict__ Wout,
                         u16* __restrict__ Wtq_hi, u16* __restrict__ Wtq_lo,
                         u16* __restrict__ Wk_hi,  u16* __restrict__ Wk_lo,
                         u16* __restrict__ Wv_hi,  u16* __restrict__ Woutb) {
  int r = blockIdx.x;              // 0..4095
  int part = r >> 10;
  int rr = r & 1023;
  int h = rr >> 6, d = rr & 63;
  const float* src;
  u16 *dh, *dl = nullptr;
  if (part == 0)      { src = Wtqkv + (size_t)(d * 48 + h) * 1024;      dh = Wtq_hi + (size_t)rr * 1024; dl = Wtq_lo + (size_t)rr * 1024; }
  else if (part == 1) { src = Wqkv  + (size_t)(d * 48 + 16 + h) * 1024; dh = Wk_hi  + (size_t)rr * 1024; dl = Wk_lo  + (size_t)rr * 1024; }
  else if (part == 2) { src = Wqkv  + (size_t)(d * 48 + 32 + h) * 1024; dh = Wv_hi  + (size_t)rr * 1024; }
  else                { src = Wout  + (size_t)rr * 1024;                dh = Woutb  + (size_t)rr * 1024; }
  int c = threadIdx.x * 4;
  f32x4 v = *(const f32x4*)&src[c];
  unsigned int hv[4], lv[4];
#pragma unroll
  for (int j = 0; j < 4; ++j) {
    u16 hb = f32_to_bf16(v[j]);
    hv[j] = hb;
    lv[j] = f32_to_bf16(v[j] - bf16_to_f32(hb));
  }
  uint2 ho; ho.x = hv[0] | (hv[1] << 16); ho.y = hv[2] | (hv[3] << 16);
  *(uint2*)&dh[c] = ho;
  if (dl) {
    uint2 lo; lo.x = lv[0] | (lv[1] << 16); lo.y = lv[2] | (lv[3] << 16);
    *(uint2*)&dl[c] = lo;
  }
}

// ---------------------------------------------------------------------------
// Hi/lo projection GEMM: C = A(M,K)f32 * B(N,K)^T (B as bf16 hi/lo planes),
// 3-MFMA hilo product; epilogue writes scale*C as bf16 hi/lo planes.
__global__ __launch_bounds__(256)
void gemm_qk(const float* __restrict__ A, const u16* __restrict__ Bh,
             const u16* __restrict__ Bl, u16* __restrict__ Chi,
             u16* __restrict__ Clo, float scale, int M, int N, int K) {
  __shared__ __align__(16) u16 Ahs[128][40];
  __shared__ __align__(16) u16 Als[128][40];
  __shared__ __align__(16) u16 Bhs[128][40];
  __shared__ __align__(16) u16 Bls[128][40];
  const int tid = threadIdx.x;
  const int wid = tid >> 6, lane = tid & 63;
  const int g = lane >> 4, l16 = lane & 15;
  const int m0 = blockIdx.y * 128, n0 = blockIdx.x * 128;
  const int wm = (wid & 1) * 64, wn = (wid >> 1) * 64;

  f32x4 acc[4][4];
  const f32x4 zero4 = {0.f, 0.f, 0.f, 0.f};
#pragma unroll
  for (int i = 0; i < 4; ++i)
#pragma unroll
    for (int j = 0; j < 4; ++j) acc[i][j] = zero4;

  for (int k0 = 0; k0 < K; k0 += 32) {
    __syncthreads();
#pragma unroll
    for (int r = 0; r < 2; ++r) {
      int idx = tid + r * 256;
      int row = idx >> 2;
      int col = (idx & 3) * 8;
      const float* ap = &A[(size_t)(m0 + row) * K + k0 + col];
      f32x4 a0 = *(const f32x4*)ap;
      f32x4 a1 = *(const f32x4*)(ap + 4);
      short8 hfr, lfr;
#pragma unroll
      for (int j = 0; j < 8; ++j) {
        float v = (j < 4) ? a0[j] : a1[j - 4];
        u16 hb = f32_to_bf16(v);
        hfr[j] = (short)hb;
        lfr[j] = (short)f32_to_bf16(v - bf16_to_f32(hb));
      }
      *(short8*)&Ahs[row][col] = hfr;
      *(short8*)&Als[row][col] = lfr;
      *(uint4*)&Bhs[row][col] = *(const uint4*)&Bh[(size_t)(n0 + row) * K + k0 + col];
      *(uint4*)&Bls[row][col] = *(const uint4*)&Bl[(size_t)(n0 + row) * K + k0 + col];
    }
    __syncthreads();
    short8 ah[4], al[4], bh4[4], bl4[4];
#pragma unroll
    for (int mi = 0; mi < 4; ++mi) {
      ah[mi] = *(const short8*)&Ahs[wm + mi * 16 + l16][g * 8];
      al[mi] = *(const short8*)&Als[wm + mi * 16 + l16][g * 8];
    }
#pragma unroll
    for (int ni = 0; ni < 4; ++ni) {
      bh4[ni] = *(const short8*)&Bhs[wn + ni * 16 + l16][g * 8];
      bl4[ni] = *(const short8*)&Bls[wn + ni * 16 + l16][g * 8];
    }
#pragma unroll
    for (int mi = 0; mi < 4; ++mi)
#pragma unroll
      for (int ni = 0; ni < 4; ++ni) {
        acc[mi][ni] = __builtin_amdgcn_mfma_f32_16x16x32_bf16(ah[mi], bh4[ni], acc[mi][ni], 0, 0, 0);
        acc[mi][ni] = __builtin_amdgcn_mfma_f32_16x16x32_bf16(ah[mi], bl4[ni], acc[mi][ni], 0, 0, 0);
        acc[mi][ni] = __builtin_amdgcn_mfma_f32_16x16x32_bf16(al[mi], bh4[ni], acc[mi][ni], 0, 0, 0);
      }
  }
  // C/D layout: col=lane&15 (n), row=(lane>>4)*4+reg (m). Dual-plane store.
#pragma unroll
  for (int mi = 0; mi < 4; ++mi)
#pragma unroll
    for (int ni = 0; ni < 4; ++ni) {
      int row = m0 + wm + mi * 16 + g * 4;
      int col = n0 + wn + ni * 16 + l16;
#pragma unroll
      for (int r = 0; r < 4; ++r) {
        float v = acc[mi][ni][r] * scale;
        u16 hb = f32_to_bf16(v);
        size_t o = (size_t)(row + r) * N + col;
        Chi[o] = hb;
        Clo[o] = f32_to_bf16(v - bf16_to_f32(hb));
      }
    }
}

// ---------------------------------------------------------------------------
// Vt GEMM: C(M=1024 feat, N=4096 t) = A(Wv bf16 plane, M x K) * B(x f32, N x K)^T.
// Produces V already transposed: Vt[(h*64+d)][b*2048+t] with plain row-major stores.
__global__ __launch_bounds__(256)
void gemm_vt(const u16* __restrict__ A, const float* __restrict__ B,
             u16* __restrict__ C, int M, int N, int K) {
  __shared__ __align__(16) u16 As[128][40];
  __shared__ __align__(16) u16 Bs[128][40];
  const int tid = threadIdx.x;
  const int wid = tid >> 6, lane = tid & 63;
  const int g = lane >> 4, l16 = lane & 15;
  const int m0 = blockIdx.y * 128, n0 = blockIdx.x * 128;
  const int wm = (wid & 1) * 64, wn = (wid >> 1) * 64;

  f32x4 acc[4][4];
  const f32x4 zero4 = {0.f, 0.f, 0.f, 0.f};
#pragma unroll
  for (int i = 0; i < 4; ++i)
#pragma unroll
    for (int j = 0; j < 4; ++j) acc[i][j] = zero4;

  for (int k0 = 0; k0 < K; k0 += 32) {
    __syncthreads();
#pragma unroll
    for (int r = 0; r < 2; ++r) {
      int idx = tid + r * 256;
      int row = idx >> 2;
      int col = (idx & 3) * 8;
      *(uint4*)&As[row][col] = *(const uint4*)&A[(size_t)(m0 + row) * K + k0 + col];
      const float* bp = &B[(size_t)(n0 + row) * K + k0 + col];
      f32x4 b0 = *(const f32x4*)bp;
      f32x4 b1 = *(const f32x4*)(bp + 4);
      short8 hfr;
#pragma unroll
      for (int j = 0; j < 8; ++j) {
        float v = (j < 4) ? b0[j] : b1[j - 4];
        hfr[j] = (short)f32_to_bf16(v);
      }
      *(short8*)&Bs[row][col] = hfr;
    }
    __syncthreads();
    short8 af[4], bfr[4];
#pragma unroll
    for (int mi = 0; mi < 4; ++mi)
      af[mi] = *(const short8*)&As[wm + mi * 16 + l16][g * 8];
#pragma unroll
    for (int ni = 0; ni < 4; ++ni)
      bfr[ni] = *(const short8*)&Bs[wn + ni * 16 + l16][g * 8];
#pragma unroll
    for (int mi = 0; mi < 4; ++mi)
#pragma unroll
      for (int ni = 0; ni < 4; ++ni)
        acc[mi][ni] = __builtin_amdgcn_mfma_f32_16x16x32_bf16(af[mi], bfr[ni], acc[mi][ni], 0, 0, 0);
  }
#pragma unroll
  for (int mi = 0; mi < 4; ++mi)
#pragma unroll
    for (int ni = 0; ni < 4; ++ni) {
      int row = m0 + wm + mi * 16 + g * 4;
      int col = n0 + wn + ni * 16 + l16;
#pragma unroll
      for (int r = 0; r < 4; ++r)
        C[(size_t)(row + r) * N + col] = f32_to_bf16(acc[mi][ni][r]);
    }
}

// ---------------------------------------------------------------------------
// Plain bf16 GEMM, f32 out (final projection).
__global__ __launch_bounds__(256)
void gemm_bt(const u16* __restrict__ A, const u16* __restrict__ B,
             float* __restrict__ C, int M, int N, int K) {
  __shared__ __align__(16) u16 As[128][40];
  __shared__ __align__(16) u16 Bs[128][40];
  const int tid = threadIdx.x;
  const int wid = tid >> 6, lane = tid & 63;
  const int g = lane >> 4, l16 = lane & 15;
  const int m0 = blockIdx.y * 128, n0 = blockIdx.x * 128;
  const int wm = (wid & 1) * 64, wn = (wid >> 1) * 64;

  f32x4 acc[4][4];
  const f32x4 zero4 = {0.f, 0.f, 0.f, 0.f};
#pragma unroll
  for (int i = 0; i < 4; ++i)
#pragma unroll
    for (int j = 0; j < 4; ++j) acc[i][j] = zero4;

  for (int k0 = 0; k0 < K; k0 += 32) {
    __syncthreads();
#pragma unroll
    for (int r = 0; r < 2; ++r) {
      int idx = tid + r * 256;
      int row = idx >> 2;
      int col = (idx & 3) * 8;
      *(uint4*)&As[row][col] = *(const uint4*)&A[(size_t)(m0 + row) * K + k0 + col];
      *(uint4*)&Bs[row][col] = *(const uint4*)&B[(size_t)(n0 + row) * K + k0 + col];
    }
    __syncthreads();
    short8 af[4], bfr[4];
#pragma unroll
    for (int mi = 0; mi < 4; ++mi)
      af[mi] = *(const short8*)&As[wm + mi * 16 + l16][g * 8];
#pragma unroll
    for (int ni = 0; ni < 4; ++ni)
      bfr[ni] = *(const short8*)&Bs[wn + ni * 16 + l16][g * 8];
#pragma unroll
    for (int mi = 0; mi < 4; ++mi)
#pragma unroll
      for (int ni = 0; ni < 4; ++ni)
        acc[mi][ni] = __builtin_amdgcn_mfma_f32_16x16x32_bf16(af[mi], bfr[ni], acc[mi][ni], 0, 0, 0);
  }
#pragma unroll
  for (int mi = 0; mi < 4; ++mi)
#pragma unroll
    for (int ni = 0; ni < 4; ++ni) {
      int row = m0 + wm + mi * 16 + g * 4;
      int col = n0 + wn + ni * 16 + l16;
#pragma unroll
      for (int r = 0; r < 4; ++r)
        C[(size_t)(row + r) * N + col] = acc[mi][ni][r];
    }
}

// ---------------------------------------------------------------------------
// Flash attention v2. Q pre-scaled by 8*log2(e) and pre-split hi/lo (global);
// K pre-split hi/lo; V pre-transposed. No conversions in the hot loop.
// Block = 128 q rows, 4 waves x 32 q (m-frag reuse doubles FLOP per LDS byte).
// 64-key chunks. All LDS rows padded to 72 u16 (9 granules) -> even bank spread.
__global__ __launch_bounds__(256)
void attn_fwd(const u16* __restrict__ Qhi, const u16* __restrict__ Qlo,
              const u16* __restrict__ Khi, const u16* __restrict__ Klo,
              const u16* __restrict__ Vt, u16* __restrict__ O) {
  const int blk = blockIdx.x;              // 512 blocks
  const int qb = blk & 15, bh = blk >> 4;
  const int h = bh & 15, b = bh >> 4;
  const int t0 = qb * 128;
  const int tid = threadIdx.x, wid = tid >> 6, lane = tid & 63;
  const int g = lane >> 4, l16 = lane & 15;

  __shared__ __align__(16) u16 Ksh[64][72];   // keys x d
  __shared__ __align__(16) u16 Ksl[64][72];
  __shared__ __align__(16) u16 Vs[64][72];    // d x keys
  __shared__ __align__(16) u16 Ps[4][32][72]; // per-wave P: q x keys

  // Persistent Q fragments: [mt][ks], rows t0+wid*32+mt*16+l16, k=ks*32+g*8+j
  short8 qh[2][2], ql[2][2];
#pragma unroll
  for (int mt = 0; mt < 2; ++mt)
#pragma unroll
    for (int ks = 0; ks < 2; ++ks) {
      size_t qo = (size_t)(b * 2048 + t0 + wid * 32 + mt * 16 + l16) * 1024
                  + h * 64 + ks * 32 + g * 8;
      qh[mt][ks] = *(const short8*)&Qhi[qo];
      ql[mt][ks] = *(const short8*)&Qlo[qo];
    }

  float mrow[2][4], lrow[2][4];
#pragma unroll
  for (int mt = 0; mt < 2; ++mt)
#pragma unroll
    for (int r = 0; r < 4; ++r) { mrow[mt][r] = -1.0e30f; lrow[mt][r] = 0.f; }
  const f32x4 zero4 = {0.f, 0.f, 0.f, 0.f};
  f32x4 acc[2][4];
#pragma unroll
  for (int mt = 0; mt < 2; ++mt)
#pragma unroll
    for (int dn = 0; dn < 4; ++dn) acc[mt][dn] = zero4;

  const size_t kbase = (size_t)(b * 2048) * 1024 + h * 64;
  const size_t vbase = (size_t)(h * 64) * 4096 + b * 2048;

  for (int j0 = 0; j0 < 2048; j0 += 64) {
    __syncthreads();
    // Stage 64 keys: Khi/Klo (keys x 64d) and Vt chunk (64d x keys). Pure b128.
    {
      int gr = tid & 7;
#pragma unroll
      for (int p = 0; p < 2; ++p) {
        int row = (tid >> 3) + p * 32;
        size_t go = kbase + (size_t)(j0 + row) * 1024 + gr * 8;
        *(uint4*)&Ksh[row][gr * 8] = *(const uint4*)&Khi[go];
        *(uint4*)&Ksl[row][gr * 8] = *(const uint4*)&Klo[go];
        *(uint4*)&Vs[row][gr * 8]  = *(const uint4*)&Vt[vbase + (size_t)row * 4096 + j0 + gr * 8];
      }
    }
    __syncthreads();

    // Scores: s[mt][n] covers q rows (wave) x keys n*16+l16, log2-domain.
    f32x4 s[2][4];
#pragma unroll
    for (int mt = 0; mt < 2; ++mt)
#pragma unroll
      for (int n = 0; n < 4; ++n) s[mt][n] = zero4;
#pragma unroll
    for (int ks = 0; ks < 2; ++ks)
#pragma unroll
      for (int n = 0; n < 4; ++n) {
        short8 kh = *(const short8*)&Ksh[n * 16 + l16][ks * 32 + g * 8];
        short8 kl = *(const short8*)&Ksl[n * 16 + l16][ks * 32 + g * 8];
        s[0][n] = __builtin_amdgcn_mfma_f32_16x16x32_bf16(qh[0][ks], kh, s[0][n], 0, 0, 0);
        s[1][n] = __builtin_amdgcn_mfma_f32_16x16x32_bf16(qh[1][ks], kh, s[1][n], 0, 0, 0);
        s[0][n] = __builtin_amdgcn_mfma_f32_16x16x32_bf16(ql[0][ks], kh, s[0][n], 0, 0, 0);
        s[1][n] = __builtin_amdgcn_mfma_f32_16x16x32_bf16(ql[1][ks], kh, s[1][n], 0, 0, 0);
        s[0][n] = __builtin_amdgcn_mfma_f32_16x16x32_bf16(qh[0][ks], kl, s[0][n], 0, 0, 0);
        s[1][n] = __builtin_amdgcn_mfma_f32_16x16x32_bf16(qh[1][ks], kl, s[1][n], 0, 0, 0);
      }

    // Online softmax (exp2 domain). Row (mt, g*4+r); reduce over 16 l16 lanes.
#pragma unroll
    for (int mt = 0; mt < 2; ++mt)
#pragma unroll
      for (int r = 0; r < 4; ++r) {
        float cm = fmaxf(fmaxf(s[mt][0][r], s[mt][1][r]),
                         fmaxf(s[mt][2][r], s[mt][3][r]));
        cm = fmaxf(cm, __shfl_xor(cm, 1));
        cm = fmaxf(cm, __shfl_xor(cm, 2));
        cm = fmaxf(cm, __shfl_xor(cm, 4));
        cm = fmaxf(cm, __shfl_xor(cm, 8));
        float mnew = fmaxf(mrow[mt][r], cm);
        float al = EXP2F(mrow[mt][r] - mnew);
        float p0 = EXP2F(s[mt][0][r] - mnew);
        float p1 = EXP2F(s[mt][1][r] - mnew);
        float p2 = EXP2F(s[mt][2][r] - mnew);
        float p3 = EXP2F(s[mt][3][r] - mnew);
        float t = (p0 + p1) + (p2 + p3);
        t += __shfl_xor(t, 1); t += __shfl_xor(t, 2);
        t += __shfl_xor(t, 4); t += __shfl_xor(t, 8);
        lrow[mt][r] = lrow[mt][r] * al + t;
        mrow[mt][r] = mnew;
#pragma unroll
        for (int dn = 0; dn < 4; ++dn) acc[mt][dn][r] *= al;
        int qr = mt * 16 + g * 4 + r;
        Ps[wid][qr][0 * 16 + l16] = f32_to_bf16(p0);
        Ps[wid][qr][1 * 16 + l16] = f32_to_bf16(p1);
        Ps[wid][qr][2 * 16 + l16] = f32_to_bf16(p2);
        Ps[wid][qr][3 * 16 + l16] = f32_to_bf16(p3);
      }
    __syncthreads();   // safety: order Ps cross-lane write->read

    // PV: P A-frags [m=q][k=key], Vs B-frags [n=d][k=key]
#pragma unroll
    for (int ks2 = 0; ks2 < 2; ++ks2) {
      short8 pa0 = *(const short8*)&Ps[wid][l16][ks2 * 32 + g * 8];
      short8 pa1 = *(const short8*)&Ps[wid][16 + l16][ks2 * 32 + g * 8];
#pragma unroll
      for (int dn = 0; dn < 4; ++dn) {
        short8 vb = *(const short8*)&Vs[dn * 16 + l16][ks2 * 32 + g * 8];
        acc[0][dn] = __builtin_amdgcn_mfma_f32_16x16x32_bf16(pa0, vb, acc[0][dn], 0, 0, 0);
        acc[1][dn] = __builtin_amdgcn_mfma_f32_16x16x32_bf16(pa1, vb, acc[1][dn], 0, 0, 0);
      }
    }
  }

  // Epilogue: O[b, t, h*64+d] bf16
#pragma unroll
  for (int mt = 0; mt < 2; ++mt)
#pragma unroll
    for (int r = 0; r < 4; ++r) {
      float inv = 1.f / lrow[mt][r];
      int row = t0 + wid * 32 + mt * 16 + g * 4 + r;
      size_t base = (size_t)(b * 2048 + row) * 1024 + h * 64;
#pragma unroll
      for (int dn = 0; dn < 4; ++dn)
        O[base + dn * 16 + l16] = f32_to_bf16(acc[mt][dn][r] * inv);
    }
}

// ---------------------------------------------------------------------------
extern "C" void kernel_launch(void* const* d_in, const int* in_sizes, int n_in,
                              void* d_out, int out_size, void* d_ws, size_t ws_size,
                              hipStream_t stream) {
  const float* x     = (const float*)d_in[0];   // (2,2048,1024) f32
  const float* tx    = (const float*)d_in[1];
  const float* Wqkv  = (const float*)d_in[2];   // (3072,1024) f32
  const float* Wtqkv = (const float*)d_in[3];
  const float* Wout  = (const float*)d_in[4];   // (1024,1024) f32
  float* out = (float*)d_out;                   // (2,2048,1024) f32

  // workspace (peak 52 MB):
  //  0 Wtq_hi | 2 Wtq_lo | 4 Wk_hi | 6 Wk_lo | 8 Wv_hi | 10 Wout_hi  (MB)
  //  12 Qhi 8MB | 20 Qlo 8 | 28 Khi 8 | 36 Klo 8 | 44 Vt 8
  //  Ob (8MB) aliases 0-8 (Wtq/Wk planes dead after projections)
  char* ws = (char*)d_ws;
  const size_t MB = 1048576;
  u16* Wtq_hi = (u16*)(ws + 0 * MB);
  u16* Wtq_lo = (u16*)(ws + 2 * MB);
  u16* Wk_hi  = (u16*)(ws + 4 * MB);
  u16* Wk_lo  = (u16*)(ws + 6 * MB);
  u16* Wv_hi  = (u16*)(ws + 8 * MB);
  u16* Woutb  = (u16*)(ws + 10 * MB);
  u16* Qhi    = (u16*)(ws + 12 * MB);
  u16* Qlo    = (u16*)(ws + 20 * MB);
  u16* Khi    = (u16*)(ws + 28 * MB);
  u16* Klo    = (u16*)(ws + 36 * MB);
  u16* Vt     = (u16*)(ws + 44 * MB);
  u16* Ob     = (u16*)(ws + 0 * MB);
  if (ws_size < 52 * MB) return;

  const float QSCALE = 8.0f * 1.4426950408889634f;  // sqrt(d)=8, log2(e) for exp2

  repack_w<<<4096, 256, 0, stream>>>(Wqkv, Wtqkv, Wout,
                                     Wtq_hi, Wtq_lo, Wk_hi, Wk_lo, Wv_hi, Woutb);
  dim3 blk(256);
  dim3 gP(1024 / 128, 4096 / 128);   // (N/128, M/128) projections
  dim3 gV(4096 / 128, 1024 / 128);   // Vt: M=1024 feat, N=4096 t
  gemm_qk<<<gP, blk, 0, stream>>>(tx, Wtq_hi, Wtq_lo, Qhi, Qlo, QSCALE, 4096, 1024, 1024);
  gemm_qk<<<gP, blk, 0, stream>>>(x,  Wk_hi,  Wk_lo,  Khi, Klo, 1.0f,   4096, 1024, 1024);
  gemm_vt<<<gV, blk, 0, stream>>>(Wv_hi, x, Vt, 1024, 4096, 1024);
  attn_fwd<<<512, blk, 0, stream>>>(Qhi, Qlo, Khi, Klo, Vt, Ob);
  gemm_bt<<<gP, blk, 0, stream>>>(Ob, Woutb, out, 4096, 1024, 1024);
}

// Round 4
// 393.496 us; speedup vs baseline: 1.2900x; 1.1216x over previous
//
#include <hip/hip_runtime.h>

// Inputs/outputs FLOAT32 per the reference. bf16 internally for MFMA (raw u16).
typedef unsigned short u16;
typedef __attribute__((ext_vector_type(8))) short short8;   // MFMA A/B frag
typedef __attribute__((ext_vector_type(4))) float f32x4;    // MFMA C/D frag

__device__ inline u16 f32_to_bf16(float f) {
  unsigned int u = __float_as_uint(f);
  u += 0x7fffu + ((u >> 16) & 1u);      // RNE
  return (u16)(u >> 16);
}
__device__ inline float bf16_to_f32(u16 s) {
  return __uint_as_float(((unsigned int)s) << 16);
}

#if __has_builtin(__builtin_amdgcn_exp2f)
#define EXP2F(x) __builtin_amdgcn_exp2f(x)
#else
#define EXP2F(x) exp2f(x)
#endif

// ---------------------------------------------------------------------------
// Weight repack + f32 -> bf16 hi/lo planes. qkv packing j = d*48 + k*16 + h.
__global__ void repack_w(const float* __restrict__ Wqkv, const float* __restrict__ Wtqkv,
                         const float* __restrict__ Wout,
                         u16* __restrict__ Wtq_hi, u16* __restrict__ Wtq_lo,
                         u16* __restrict__ Wk_hi,  u16* __restrict__ Wk_lo,
                         u16* __restrict__ Wv_hi,  u16* __restrict__ Woutb) {
  int r = blockIdx.x;              // 0..4095
  int part = r >> 10;
  int rr = r & 1023;
  int h = rr >> 6, d = rr & 63;
  const float* src;
  u16 *dh, *dl = nullptr;
  if (part == 0)      { src = Wtqkv + (size_t)(d * 48 + h) * 1024;      dh = Wtq_hi + (size_t)rr * 1024; dl = Wtq_lo + (size_t)rr * 1024; }
  else if (part == 1) { src = Wqkv  + (size_t)(d * 48 + 16 + h) * 1024; dh = Wk_hi  + (size_t)rr * 1024; dl = Wk_lo  + (size_t)rr * 1024; }
  else if (part == 2) { src = Wqkv  + (size_t)(d * 48 + 32 + h) * 1024; dh = Wv_hi  + (size_t)rr * 1024; }
  else                { src = Wout  + (size_t)rr * 1024;                dh = Woutb  + (size_t)rr * 1024; }
  int c = threadIdx.x * 4;
  f32x4 v = *(const f32x4*)&src[c];
  unsigned int hv[4], lv[4];
#pragma unroll
  for (int j = 0; j < 4; ++j) {
    u16 hb = f32_to_bf16(v[j]);
    hv[j] = hb;
    lv[j] = f32_to_bf16(v[j] - bf16_to_f32(hb));
  }
  uint2 ho; ho.x = hv[0] | (hv[1] << 16); ho.y = hv[2] | (hv[3] << 16);
  *(uint2*)&dh[c] = ho;
  if (dl) {
    uint2 lo; lo.x = lv[0] | (lv[1] << 16); lo.y = lv[2] | (lv[3] << 16);
    *(uint2*)&dl[c] = lo;
  }
}

// ---------------------------------------------------------------------------
// Fused projection GEMM. grid = (256 tiles, 3 jobs). 768 blocks -> 3/CU.
// job 0: Q = tx @ Wtq^T * QSCALE  -> Qhi/Qlo planes (hilo 3-MFMA), M=4096,N=1024
// job 1: K = x  @ Wk^T            -> Khi/Klo planes (hilo 3-MFMA)
// job 2: Vt = Wv_hi @ x^T (bf16)  -> Vt[feat][t],   M=1024,N=4096 (1 MFMA)
__global__ __launch_bounds__(256)
void proj_fused(const float* __restrict__ x, const float* __restrict__ tx,
                const u16* __restrict__ Wtq_hi, const u16* __restrict__ Wtq_lo,
                const u16* __restrict__ Wk_hi,  const u16* __restrict__ Wk_lo,
                const u16* __restrict__ Wv_hi,
                u16* __restrict__ Qhi, u16* __restrict__ Qlo,
                u16* __restrict__ Khi, u16* __restrict__ Klo,
                u16* __restrict__ Vt, float qscale) {
  __shared__ __align__(16) u16 Ahs[128][40];
  __shared__ __align__(16) u16 Als[128][40];
  __shared__ __align__(16) u16 Bhs[128][40];
  __shared__ __align__(16) u16 Bls[128][40];
  const int tid = threadIdx.x;
  const int wid = tid >> 6, lane = tid & 63;
  const int g = lane >> 4, l16 = lane & 15;
  const int job = blockIdx.y;
  const int tile = blockIdx.x;
  const int wm = (wid & 1) * 64, wn = (wid >> 1) * 64;
  const int K = 1024;

  int m0, n0, N;
  const float* Af = nullptr;        // f32 A (jobs 0/1) / f32 B (job 2)
  const u16 *Bh = nullptr, *Bl = nullptr;
  if (job == 0) { m0 = (tile >> 3) * 128; n0 = (tile & 7) * 128; N = 1024; Af = tx; Bh = Wtq_hi; Bl = Wtq_lo; }
  else if (job == 1) { m0 = (tile >> 3) * 128; n0 = (tile & 7) * 128; N = 1024; Af = x; Bh = Wk_hi; Bl = Wk_lo; }
  else { m0 = (tile >> 5) * 128; n0 = (tile & 31) * 128; N = 4096; Af = x; Bh = Wv_hi; }

  f32x4 acc[4][4];
  const f32x4 zero4 = {0.f, 0.f, 0.f, 0.f};
#pragma unroll
  for (int i = 0; i < 4; ++i)
#pragma unroll
    for (int j = 0; j < 4; ++j) acc[i][j] = zero4;

  for (int k0 = 0; k0 < K; k0 += 32) {
    __syncthreads();
#pragma unroll
    for (int r = 0; r < 2; ++r) {
      int idx = tid + r * 256;
      int row = idx >> 2;
      int col = (idx & 3) * 8;
      if (job != 2) {
        // A: f32 -> hilo split; B: preconverted planes
        const float* ap = &Af[(size_t)(m0 + row) * K + k0 + col];
        f32x4 a0 = *(const f32x4*)ap;
        f32x4 a1 = *(const f32x4*)(ap + 4);
        short8 hfr, lfr;
#pragma unroll
        for (int j = 0; j < 8; ++j) {
          float v = (j < 4) ? a0[j] : a1[j - 4];
          u16 hb = f32_to_bf16(v);
          hfr[j] = (short)hb;
          lfr[j] = (short)f32_to_bf16(v - bf16_to_f32(hb));
        }
        *(short8*)&Ahs[row][col] = hfr;
        *(short8*)&Als[row][col] = lfr;
        *(uint4*)&Bhs[row][col] = *(const uint4*)&Bh[(size_t)(n0 + row) * K + k0 + col];
        *(uint4*)&Bls[row][col] = *(const uint4*)&Bl[(size_t)(n0 + row) * K + k0 + col];
      } else {
        // A: Wv bf16 plane direct; B: x f32 -> bf16 (RNE)
        *(uint4*)&Ahs[row][col] = *(const uint4*)&Bh[(size_t)(m0 + row) * K + k0 + col];
        const float* bp = &Af[(size_t)(n0 + row) * K + k0 + col];
        f32x4 b0 = *(const f32x4*)bp;
        f32x4 b1 = *(const f32x4*)(bp + 4);
        short8 hfr;
#pragma unroll
        for (int j = 0; j < 8; ++j) {
          float v = (j < 4) ? b0[j] : b1[j - 4];
          hfr[j] = (short)f32_to_bf16(v);
        }
        *(short8*)&Bhs[row][col] = hfr;
      }
    }
    __syncthreads();
    if (job != 2) {
      short8 ah[4], al[4], bh4[4], bl4[4];
#pragma unroll
      for (int mi = 0; mi < 4; ++mi) {
        ah[mi] = *(const short8*)&Ahs[wm + mi * 16 + l16][g * 8];
        al[mi] = *(const short8*)&Als[wm + mi * 16 + l16][g * 8];
      }
#pragma unroll
      for (int ni = 0; ni < 4; ++ni) {
        bh4[ni] = *(const short8*)&Bhs[wn + ni * 16 + l16][g * 8];
        bl4[ni] = *(const short8*)&Bls[wn + ni * 16 + l16][g * 8];
      }
#pragma unroll
      for (int mi = 0; mi < 4; ++mi)
#pragma unroll
        for (int ni = 0; ni < 4; ++ni) {
          acc[mi][ni] = __builtin_amdgcn_mfma_f32_16x16x32_bf16(ah[mi], bh4[ni], acc[mi][ni], 0, 0, 0);
          acc[mi][ni] = __builtin_amdgcn_mfma_f32_16x16x32_bf16(ah[mi], bl4[ni], acc[mi][ni], 0, 0, 0);
          acc[mi][ni] = __builtin_amdgcn_mfma_f32_16x16x32_bf16(al[mi], bh4[ni], acc[mi][ni], 0, 0, 0);
        }
    } else {
      short8 af[4], bfr[4];
#pragma unroll
      for (int mi = 0; mi < 4; ++mi)
        af[mi] = *(const short8*)&Ahs[wm + mi * 16 + l16][g * 8];
#pragma unroll
      for (int ni = 0; ni < 4; ++ni)
        bfr[ni] = *(const short8*)&Bhs[wn + ni * 16 + l16][g * 8];
#pragma unroll
      for (int mi = 0; mi < 4; ++mi)
#pragma unroll
        for (int ni = 0; ni < 4; ++ni)
          acc[mi][ni] = __builtin_amdgcn_mfma_f32_16x16x32_bf16(af[mi], bfr[ni], acc[mi][ni], 0, 0, 0);
    }
  }
  // Epilogue. C/D: col=l16 (n), row=g*4+reg (m).
  u16* Chi = (job == 0) ? Qhi : ((job == 1) ? Khi : Vt);
  u16* Clo = (job == 0) ? Qlo : Klo;
  float scale = (job == 0) ? qscale : 1.0f;
#pragma unroll
  for (int mi = 0; mi < 4; ++mi)
#pragma unroll
    for (int ni = 0; ni < 4; ++ni) {
      int row = m0 + wm + mi * 16 + g * 4;
      int col = n0 + wn + ni * 16 + l16;
#pragma unroll
      for (int r = 0; r < 4; ++r) {
        float v = acc[mi][ni][r] * scale;
        size_t o = (size_t)(row + r) * N + col;
        if (job != 2) {
          u16 hb = f32_to_bf16(v);
          Chi[o] = hb;
          Clo[o] = f32_to_bf16(v - bf16_to_f32(hb));
        } else {
          Chi[o] = f32_to_bf16(v);
        }
      }
    }
}

// ---------------------------------------------------------------------------
// Final projection: C(f32) = A(M,K)bf16 * B(N,K)^T bf16. 128x64 tile -> 512 blk.
__global__ __launch_bounds__(256)
void gemm_out(const u16* __restrict__ A, const u16* __restrict__ B,
              float* __restrict__ C, int M, int N, int K) {
  __shared__ __align__(16) u16 As[128][40];
  __shared__ __align__(16) u16 Bs[64][40];
  const int tid = threadIdx.x;
  const int wid = tid >> 6, lane = tid & 63;
  const int g = lane >> 4, l16 = lane & 15;
  const int m0 = blockIdx.y * 128, n0 = blockIdx.x * 64;
  const int wm = (wid & 1) * 64, wn = (wid >> 1) * 32;

  f32x4 acc[4][2];
  const f32x4 zero4 = {0.f, 0.f, 0.f, 0.f};
#pragma unroll
  for (int i = 0; i < 4; ++i)
#pragma unroll
    for (int j = 0; j < 2; ++j) acc[i][j] = zero4;

  for (int k0 = 0; k0 < K; k0 += 32) {
    __syncthreads();
#pragma unroll
    for (int r = 0; r < 2; ++r) {
      int idx = tid + r * 256;
      int row = idx >> 2;
      int col = (idx & 3) * 8;
      *(uint4*)&As[row][col] = *(const uint4*)&A[(size_t)(m0 + row) * K + k0 + col];
    }
    {
      int row = tid >> 2, col = (tid & 3) * 8;
      *(uint4*)&Bs[row][col] = *(const uint4*)&B[(size_t)(n0 + row) * K + k0 + col];
    }
    __syncthreads();
    short8 af[4], bfr[2];
#pragma unroll
    for (int mi = 0; mi < 4; ++mi)
      af[mi] = *(const short8*)&As[wm + mi * 16 + l16][g * 8];
#pragma unroll
    for (int ni = 0; ni < 2; ++ni)
      bfr[ni] = *(const short8*)&Bs[wn + ni * 16 + l16][g * 8];
#pragma unroll
    for (int mi = 0; mi < 4; ++mi)
#pragma unroll
      for (int ni = 0; ni < 2; ++ni)
        acc[mi][ni] = __builtin_amdgcn_mfma_f32_16x16x32_bf16(af[mi], bfr[ni], acc[mi][ni], 0, 0, 0);
  }
#pragma unroll
  for (int mi = 0; mi < 4; ++mi)
#pragma unroll
    for (int ni = 0; ni < 2; ++ni) {
      int row = m0 + wm + mi * 16 + g * 4;
      int col = n0 + wn + ni * 16 + l16;
#pragma unroll
      for (int r = 0; r < 4; ++r)
        C[(size_t)(row + r) * N + col] = acc[mi][ni][r];
    }
}

// ---------------------------------------------------------------------------
// Flash attention v3: single barrier per 64-key chunk (double-buffered LDS,
// global loads for chunk i+1 issued before compute of chunk i, ds_writes after).
// Row-sum via all-ones V rows (5th n-tile of PV) -> no sum shuffles, l rides in acc.
// P stored truncated (consistent: l computed from same truncated P via MFMA).
__global__ __launch_bounds__(256)
void attn_fwd(const u16* __restrict__ Qhi, const u16* __restrict__ Qlo,
              const u16* __restrict__ Khi, const u16* __restrict__ Klo,
              const u16* __restrict__ Vt, u16* __restrict__ O) {
  const int blk = blockIdx.x;              // 512 blocks
  const int qb = blk & 15, bh = blk >> 4;
  const int h = bh & 15, b = bh >> 4;
  const int t0 = qb * 128;
  const int tid = threadIdx.x, wid = tid >> 6, lane = tid & 63;
  const int g = lane >> 4, l16 = lane & 15;

  __shared__ __align__(16) u16 Ksh[2][64][72];
  __shared__ __align__(16) u16 Ksl[2][64][72];
  __shared__ __align__(16) u16 Vs[2][80][72];   // rows 64..79 = ones (row sums)
  __shared__ __align__(16) u16 Ps[4][32][72];   // per-wave P (no barrier needed)

  // ones rows (constant across chunks, both buffers)
  for (int i = tid; i < 16 * 72; i += 256) {
    int r = i / 72, c = i % 72;
    Vs[0][64 + r][c] = 0x3f80;
    Vs[1][64 + r][c] = 0x3f80;
  }

  // Persistent Q frags: rows t0+wid*32+mt*16+l16, k = ks*32+g*8+j
  short8 qh[2][2], ql[2][2];
#pragma unroll
  for (int mt = 0; mt < 2; ++mt)
#pragma unroll
    for (int ks = 0; ks < 2; ++ks) {
      size_t qo = (size_t)(b * 2048 + t0 + wid * 32 + mt * 16 + l16) * 1024
                  + h * 64 + ks * 32 + g * 8;
      qh[mt][ks] = *(const short8*)&Qhi[qo];
      ql[mt][ks] = *(const short8*)&Qlo[qo];
    }

  float mrow[2][4];
#pragma unroll
  for (int mt = 0; mt < 2; ++mt)
#pragma unroll
    for (int r = 0; r < 4; ++r) mrow[mt][r] = -1.0e30f;
  const f32x4 zero4 = {0.f, 0.f, 0.f, 0.f};
  f32x4 acc[2][5];   // [][4] = row-sum column (ones rows)
#pragma unroll
  for (int mt = 0; mt < 2; ++mt)
#pragma unroll
    for (int dn = 0; dn < 5; ++dn) acc[mt][dn] = zero4;

  const size_t kbase = (size_t)(b * 2048) * 1024 + h * 64;
  const size_t vbase = (size_t)(h * 64) * 4096 + b * 2048;
  const int gr = tid & 7;
  const int srow = tid >> 3;               // 0..31

  // Prologue: stage chunk 0 into buffer 0.
  {
#pragma unroll
    for (int p = 0; p < 2; ++p) {
      int row = srow + p * 32;
      size_t go = kbase + (size_t)row * 1024 + gr * 8;
      uint4 a = *(const uint4*)&Khi[go];
      uint4 bb = *(const uint4*)&Klo[go];
      uint4 c = *(const uint4*)&Vt[vbase + (size_t)row * 4096 + gr * 8];
      *(uint4*)&Ksh[0][row][gr * 8] = a;
      *(uint4*)&Ksl[0][row][gr * 8] = bb;
      *(uint4*)&Vs[0][row][gr * 8] = c;
    }
  }

  for (int i = 0; i < 32; ++i) {
    const int p = i & 1;
    __syncthreads();   // buf p complete; buf 1-p free to overwrite

    // issue next chunk's global loads (latency hidden behind compute below)
    uint4 nk[2], nl[2], nv[2];
    if (i < 31) {
      int j0n = (i + 1) * 64;
#pragma unroll
      for (int pp = 0; pp < 2; ++pp) {
        int row = srow + pp * 32;
        size_t go = kbase + (size_t)(j0n + row) * 1024 + gr * 8;
        nk[pp] = *(const uint4*)&Khi[go];
        nl[pp] = *(const uint4*)&Klo[go];
        nv[pp] = *(const uint4*)&Vt[vbase + (size_t)row * 4096 + j0n + gr * 8];
      }
    }

    // Scores (log2 domain; Q pre-scaled by 8*log2e)
    f32x4 s[2][4];
#pragma unroll
    for (int mt = 0; mt < 2; ++mt)
#pragma unroll
      for (int n = 0; n < 4; ++n) s[mt][n] = zero4;
#pragma unroll
    for (int ks = 0; ks < 2; ++ks)
#pragma unroll
      for (int n = 0; n < 4; ++n) {
        short8 kh = *(const short8*)&Ksh[p][n * 16 + l16][ks * 32 + g * 8];
        short8 kl = *(const short8*)&Ksl[p][n * 16 + l16][ks * 32 + g * 8];
        s[0][n] = __builtin_amdgcn_mfma_f32_16x16x32_bf16(qh[0][ks], kh, s[0][n], 0, 0, 0);
        s[1][n] = __builtin_amdgcn_mfma_f32_16x16x32_bf16(qh[1][ks], kh, s[1][n], 0, 0, 0);
        s[0][n] = __builtin_amdgcn_mfma_f32_16x16x32_bf16(ql[0][ks], kh, s[0][n], 0, 0, 0);
        s[1][n] = __builtin_amdgcn_mfma_f32_16x16x32_bf16(ql[1][ks], kh, s[1][n], 0, 0, 0);
        s[0][n] = __builtin_amdgcn_mfma_f32_16x16x32_bf16(qh[0][ks], kl, s[0][n], 0, 0, 0);
        s[1][n] = __builtin_amdgcn_mfma_f32_16x16x32_bf16(qh[1][ks], kl, s[1][n], 0, 0, 0);
      }

    // Online softmax (max only; sums via ones-rows in PV). exp2 domain.
#pragma unroll
    for (int mt = 0; mt < 2; ++mt)
#pragma unroll
      for (int r = 0; r < 4; ++r) {
        float cm = fmaxf(fmaxf(s[mt][0][r], s[mt][1][r]),
                         fmaxf(s[mt][2][r], s[mt][3][r]));
        cm = fmaxf(cm, __shfl_xor(cm, 1));
        cm = fmaxf(cm, __shfl_xor(cm, 2));
        cm = fmaxf(cm, __shfl_xor(cm, 4));
        cm = fmaxf(cm, __shfl_xor(cm, 8));
        float mnew = fmaxf(mrow[mt][r], cm);
        float al = EXP2F(mrow[mt][r] - mnew);
        mrow[mt][r] = mnew;
#pragma unroll
        for (int dn = 0; dn < 5; ++dn) acc[mt][dn][r] *= al;
        int qr = mt * 16 + g * 4 + r;
#pragma unroll
        for (int n = 0; n < 4; ++n) {
          float pv = EXP2F(s[mt][n][r] - mnew);
          Ps[wid][qr][n * 16 + l16] = (u16)(__float_as_uint(pv) >> 16);  // trunc
        }
      }

    // PV: P A-frags [m=q][k=key]; Vs B-frags [n=d (+ones tile)][k=key]
#pragma unroll
    for (int ks2 = 0; ks2 < 2; ++ks2) {
      short8 pa0 = *(const short8*)&Ps[wid][l16][ks2 * 32 + g * 8];
      short8 pa1 = *(const short8*)&Ps[wid][16 + l16][ks2 * 32 + g * 8];
#pragma unroll
      for (int dn = 0; dn < 5; ++dn) {
        short8 vb = *(const short8*)&Vs[p][dn * 16 + l16][ks2 * 32 + g * 8];
        acc[0][dn] = __builtin_amdgcn_mfma_f32_16x16x32_bf16(pa0, vb, acc[0][dn], 0, 0, 0);
        acc[1][dn] = __builtin_amdgcn_mfma_f32_16x16x32_bf16(pa1, vb, acc[1][dn], 0, 0, 0);
      }
    }

    // write next chunk into the other buffer (vmcnt wait lands here, post-compute)
    if (i < 31) {
#pragma unroll
      for (int pp = 0; pp < 2; ++pp) {
        int row = srow + pp * 32;
        *(uint4*)&Ksh[1 - p][row][gr * 8] = nk[pp];
        *(uint4*)&Ksl[1 - p][row][gr * 8] = nl[pp];
        *(uint4*)&Vs[1 - p][row][gr * 8] = nv[pp];
      }
    }
  }

  // Epilogue: O[b, t, h*64+d] bf16; l = acc[mt][4] (all lanes identical per r)
#pragma unroll
  for (int mt = 0; mt < 2; ++mt)
#pragma unroll
    for (int r = 0; r < 4; ++r) {
      float inv = 1.f / acc[mt][4][r];
      int row = t0 + wid * 32 + mt * 16 + g * 4 + r;
      size_t base = (size_t)(b * 2048 + row) * 1024 + h * 64;
#pragma unroll
      for (int dn = 0; dn < 4; ++dn)
        O[base + dn * 16 + l16] = f32_to_bf16(acc[mt][dn][r] * inv);
    }
}

// ---------------------------------------------------------------------------
extern "C" void kernel_launch(void* const* d_in, const int* in_sizes, int n_in,
                              void* d_out, int out_size, void* d_ws, size_t ws_size,
                              hipStream_t stream) {
  const float* x     = (const float*)d_in[0];   // (2,2048,1024) f32
  const float* tx    = (const float*)d_in[1];
  const float* Wqkv  = (const float*)d_in[2];   // (3072,1024) f32
  const float* Wtqkv = (const float*)d_in[3];
  const float* Wout  = (const float*)d_in[4];   // (1024,1024) f32
  float* out = (float*)d_out;                   // (2,2048,1024) f32

  // workspace (peak 52 MB):
  //  0 Wtq_hi | 2 Wtq_lo | 4 Wk_hi | 6 Wk_lo | 8 Wv_hi | 10 Wout_hi  (MB)
  //  12 Qhi 8 | 20 Qlo 8 | 28 Khi 8 | 36 Klo 8 | 44 Vt 8
  //  Ob (8MB) aliases 0-8 (Wtq/Wk planes dead after projections)
  char* ws = (char*)d_ws;
  const size_t MB = 1048576;
  u16* Wtq_hi = (u16*)(ws + 0 * MB);
  u16* Wtq_lo = (u16*)(ws + 2 * MB);
  u16* Wk_hi  = (u16*)(ws + 4 * MB);
  u16* Wk_lo  = (u16*)(ws + 6 * MB);
  u16* Wv_hi  = (u16*)(ws + 8 * MB);
  u16* Woutb  = (u16*)(ws + 10 * MB);
  u16* Qhi    = (u16*)(ws + 12 * MB);
  u16* Qlo    = (u16*)(ws + 20 * MB);
  u16* Khi    = (u16*)(ws + 28 * MB);
  u16* Klo    = (u16*)(ws + 36 * MB);
  u16* Vt     = (u16*)(ws + 44 * MB);
  u16* Ob     = (u16*)(ws + 0 * MB);
  if (ws_size < 52 * MB) return;

  const float QSCALE = 8.0f * 1.4426950408889634f;  // sqrt(d)=8, log2(e)

  repack_w<<<4096, 256, 0, stream>>>(Wqkv, Wtqkv, Wout,
                                     Wtq_hi, Wtq_lo, Wk_hi, Wk_lo, Wv_hi, Woutb);
  proj_fused<<<dim3(256, 3), 256, 0, stream>>>(x, tx, Wtq_hi, Wtq_lo, Wk_hi, Wk_lo,
                                               Wv_hi, Qhi, Qlo, Khi, Klo, Vt, QSCALE);
  attn_fwd<<<512, 256, 0, stream>>>(Qhi, Qlo, Khi, Klo, Vt, Ob);
  gemm_out<<<dim3(16, 32), 256, 0, stream>>>(Ob, Woutb, out, 4096, 1024, 1024);
}